// Round 3
// baseline (302.780 us; speedup 1.0000x reference)
//
#include <hip/hip_runtime.h>
#include <cstdint>
#include <cstddef>

#define BB 64
#define PP 24564
#define OO 16
#define NC 21
#define TPB 256
#define TPD 1024
#define NPT 24  /* ceil(PP/TPD) for topk */

// match kernel geometry
#define MB 4     /* blocks per batch */
#define MT 1024  /* threads per match block */
#define MPT 6    /* priors per thread: MB*MT*MPT = 24576 >= PP */

// ---------------- workspace layout (bytes) ----------------
static constexpr size_t OFF_ACCL = 0;      // double[64]
static constexpr size_t OFF_ACCC = 512;    // double[64]
static constexpr size_t OFF_NP   = 1024;   // int[64]
static constexpr size_t OFF_CNT  = 1280;   // int
static constexpr size_t OFF_TOPC = 1536;   // double[64]
static constexpr size_t OFF_KP   = 2048;   // u64[BB*OO*MB] = 32768 B
static constexpr size_t OFF_LH   = 36864;  // float[BB*PP]

// ---------------- Pass A: per-truth best-prior partials + init ------------
__global__ __launch_bounds__(MT) void match_kernel(
    const float* __restrict__ priors, const float* __restrict__ targets,
    unsigned long long* __restrict__ keys_part,
    double* __restrict__ accL, double* __restrict__ accC,
    int* __restrict__ num_pos, int* __restrict__ cnt) {
  const int b = blockIdx.y;
  const int bx = blockIdx.x;
  // init small accumulators (runs in pass A; pass B orders after via stream)
  if (b == 0 && bx == 0 && threadIdx.x < BB) {
    accL[threadIdx.x] = 0.0;
    accC[threadIdx.x] = 0.0;
    num_pos[threadIdx.x] = 0;
    if (threadIdx.x == 0) *cnt = 0;
  }
  __shared__ float tr[OO * 5];
  __shared__ unsigned long long red[16 * OO];  // [t][wave]
  if (threadIdx.x < OO * 5) tr[threadIdx.x] = targets[b * OO * 5 + threadIdx.x];
  __syncthreads();

  unsigned long long k16[OO];
  #pragma unroll
  for (int t = 0; t < OO; ++t) k16[t] = 0ull;

  #pragma unroll
  for (int i = 0; i < MPT; ++i) {
    const int p = bx * MT + threadIdx.x + i * (MB * MT);
    if (p < PP) {
      float4 pr = reinterpret_cast<const float4*>(priors)[p];
      float ax1 = pr.x - pr.z * 0.5f, ay1 = pr.y - pr.w * 0.5f;
      float ax2 = pr.x + pr.z * 0.5f, ay2 = pr.y + pr.w * 0.5f;
      float area_p = (ax2 - ax1) * (ay2 - ay1);
      const unsigned long long plo =
          (unsigned long long)(0xFFFFFFFFu - (unsigned)p);
      #pragma unroll
      for (int t = 0; t < OO; ++t) {
        float tx1 = tr[t * 5 + 0], ty1 = tr[t * 5 + 1];
        float tx2 = tr[t * 5 + 2], ty2 = tr[t * 5 + 3];
        float lx = fmaxf(tx1, ax1), ly = fmaxf(ty1, ay1);
        float rx = fminf(tx2, ax2), ry = fminf(ty2, ay2);
        float iw = fmaxf(rx - lx, 0.f), ih = fmaxf(ry - ly, 0.f);
        float inter = iw * ih;
        float area_t = (tx2 - tx1) * (ty2 - ty1);
        float iou = inter / (area_t + area_p - inter);
        unsigned long long key =
            ((unsigned long long)__float_as_uint(iou) << 32) | plo;
        if (key > k16[t]) k16[t] = key;
      }
    }
  }

  const int lane = threadIdx.x & 63, wid = threadIdx.x >> 6;
  #pragma unroll
  for (int t = 0; t < OO; ++t) {
    unsigned long long k = k16[t];
    for (int off = 32; off; off >>= 1) {
      unsigned long long o = __shfl_down(k, off, 64);
      if (o > k) k = o;
    }
    if (lane == 0) red[t * 16 + wid] = k;
  }
  __syncthreads();
  if (threadIdx.x < OO) {
    unsigned long long m = red[threadIdx.x * 16];
    #pragma unroll
    for (int w = 1; w < 16; ++w) {
      unsigned long long o = red[threadIdx.x * 16 + w];
      if (o > m) m = o;
    }
    keys_part[(b * OO + threadIdx.x) * MB + bx] = m;
  }
}

// ---------------- Pass B: CE + smooth-L1 + loss_hard (match recomputed) ----
__global__ __launch_bounds__(TPB) void loss_kernel(
    const float* __restrict__ loc, const float* __restrict__ conf,
    const float* __restrict__ priors, const float* __restrict__ targets,
    const unsigned long long* __restrict__ keys_part,
    float* __restrict__ lh, double* __restrict__ accL,
    double* __restrict__ accC, int* __restrict__ num_pos) {
  const int b = blockIdx.y;
  const int p0 = blockIdx.x * TPB;
  const int p = p0 + threadIdx.x;
  __shared__ float sc[TPB * NC];
  __shared__ float tr[OO * 5];
  __shared__ int fp[OO];
  __shared__ float rc[TPB / 64], rl[TPB / 64];
  __shared__ int rn[TPB / 64];
  if (threadIdx.x < OO * 5) tr[threadIdx.x] = targets[b * OO * 5 + threadIdx.x];
  if (threadIdx.x < OO) {
    const unsigned long long* kp = &keys_part[(b * OO + threadIdx.x) * MB];
    unsigned long long k = kp[0];
    #pragma unroll
    for (int j = 1; j < MB; ++j) if (kp[j] > k) k = kp[j];
    unsigned pp = 0xFFFFFFFFu - (unsigned)(k & 0xFFFFFFFFu);
    fp[threadIdx.x] = (pp < PP) ? (int)pp : -1;
  }
  const int nvalid = min(TPB, PP - p0);
  {
    const float4* cb4 =
        reinterpret_cast<const float4*>(conf + ((size_t)b * PP + p0) * NC);
    float4* sc4 = reinterpret_cast<float4*>(sc);
    const int n4 = nvalid * NC / 4;  // nvalid*21 is divisible by 4 (256/244)
    for (int i = threadIdx.x; i < n4; i += TPB) sc4[i] = cb4[i];
  }
  __syncthreads();

  float ce = 0.f, l_part = 0.f;
  bool pos = false;
  if (p < PP) {
    float4 pr = reinterpret_cast<const float4*>(priors)[p];
    float ax1 = pr.x - pr.z * 0.5f, ay1 = pr.y - pr.w * 0.5f;
    float ax2 = pr.x + pr.z * 0.5f, ay2 = pr.y + pr.w * 0.5f;
    float area_p = (ax2 - ax1) * (ay2 - ay1);
    float best = -1.0f; int bt = 0;
    #pragma unroll
    for (int t = 0; t < OO; ++t) {
      float tx1 = tr[t * 5 + 0], ty1 = tr[t * 5 + 1];
      float tx2 = tr[t * 5 + 2], ty2 = tr[t * 5 + 3];
      float lx = fmaxf(tx1, ax1), ly = fmaxf(ty1, ay1);
      float rx = fminf(tx2, ax2), ry = fminf(ty2, ay2);
      float iw = fmaxf(rx - lx, 0.f), ih = fmaxf(ry - ly, 0.f);
      float inter = iw * ih;
      float area_t = (tx2 - tx1) * (ty2 - ty1);
      float iou = inter / (area_t + area_p - inter);
      if (iou > best) { best = iou; bt = t; }  // first-max wins
    }
    float ov = best; int t = bt;
    #pragma unroll
    for (int j = 0; j < OO; ++j) {  // ascending, last-wins (matches scatter)
      if (fp[j] == p) { ov = 2.0f; t = j; }
    }

    const float* cv = &sc[threadIdx.x * NC];
    float m = cv[0];
    #pragma unroll
    for (int i = 1; i < NC; ++i) m = fmaxf(m, cv[i]);
    float s = 0.f;
    #pragma unroll
    for (int i = 0; i < NC; ++i) s += __expf(cv[i] - m);
    float lse = m + __logf(s);

    int lbl = (int)tr[t * 5 + 4];
    int c = (ov < 0.5f) ? 0 : (lbl + 1);
    ce = lse - cv[c];
    pos = (c > 0);
    lh[(size_t)b * PP + p] = pos ? 0.f : ce;

    if (pos) {
      float tx1 = tr[t * 5 + 0], ty1 = tr[t * 5 + 1];
      float tx2 = tr[t * 5 + 2], ty2 = tr[t * 5 + 3];
      float g0 = ((tx1 + tx2) * 0.5f - pr.x) / (0.1f * pr.z);
      float g1 = ((ty1 + ty2) * 0.5f - pr.y) / (0.1f * pr.w);
      float g2 = __logf((tx2 - tx1) / pr.z) / 0.2f;
      float g3 = __logf((ty2 - ty1) / pr.w) / 0.2f;
      float4 lv = reinterpret_cast<const float4*>(loc)[(size_t)b * PP + p];
      float g[4] = {g0, g1, g2, g3};
      float l[4] = {lv.x, lv.y, lv.z, lv.w};
      #pragma unroll
      for (int i = 0; i < 4; ++i) {
        float d = l[i] - g[i];
        float ad = fabsf(d);
        l_part += (ad < 1.f) ? 0.5f * d * d : (ad - 0.5f);
      }
    }
  }

  float cp = pos ? ce : 0.f;
  int cnt = pos ? 1 : 0;
  for (int off = 32; off; off >>= 1) {
    cp += __shfl_down(cp, off, 64);
    l_part += __shfl_down(l_part, off, 64);
    cnt += __shfl_down(cnt, off, 64);
  }
  const int lane = threadIdx.x & 63, wid = threadIdx.x >> 6;
  if (lane == 0) { rc[wid] = cp; rl[wid] = l_part; rn[wid] = cnt; }
  __syncthreads();
  if (threadIdx.x == 0) {
    float csum = 0.f, lsum = 0.f; int n = 0;
    for (int i = 0; i < TPB / 64; ++i) { csum += rc[i]; lsum += rl[i]; n += rn[i]; }
    if (lsum != 0.f) atomicAdd(&accL[b], (double)lsum);
    if (csum != 0.f) atomicAdd(&accC[b], (double)csum);
    if (n) atomicAdd(&num_pos[b], n);
  }
}

// ---------------- Pass C: per-batch top-K sum + fused finalize -------------
__global__ __launch_bounds__(TPD) void topk_kernel(
    const float* __restrict__ lh, const int* __restrict__ num_pos,
    double* __restrict__ topC, const double* __restrict__ accL,
    const double* __restrict__ accC, int* __restrict__ cnt,
    float* __restrict__ out) {
  const int b = blockIdx.x;
  const int np = num_pos[b];
  const int K = min(3 * np, PP - 1);
  const int lane = threadIdx.x & 63, wid = threadIdx.x >> 6;

  double contrib = 0.0;
  if (K > 0) {
    unsigned bits[NPT];
    const float* base = lh + (size_t)b * PP;
    #pragma unroll
    for (int i = 0; i < NPT; ++i) {
      int idx = threadIdx.x + i * TPD;
      bits[i] = (idx < PP) ? __float_as_uint(base[idx]) : 0u;
    }

    __shared__ int rcnt[2][TPD / 64];
    // largest T with count(bits >= T) >= K  → T = bits of K-th largest
    unsigned lo = 0u, hi = 0x7F800000u;
    int par = 0;
    while (lo < hi) {
      unsigned mid = lo + (hi - lo + 1) / 2;
      int c = 0;
      #pragma unroll
      for (int i = 0; i < NPT; ++i) c += (bits[i] >= mid) ? 1 : 0;
      for (int off = 32; off; off >>= 1) c += __shfl_down(c, off, 64);
      if (lane == 0) rcnt[par][wid] = c;
      __syncthreads();
      int tot = 0;
      #pragma unroll
      for (int i = 0; i < TPD / 64; ++i) tot += rcnt[par][i];
      if (tot >= K) lo = mid; else hi = mid - 1;
      par ^= 1;
    }
    const unsigned Tk = lo;
    const float vk = __uint_as_float(Tk);

    float s = 0.f; int cgt = 0;
    #pragma unroll
    for (int i = 0; i < NPT; ++i) {
      if (bits[i] > Tk) { s += __uint_as_float(bits[i]); ++cgt; }
    }
    double sd = (double)s;
    for (int off = 32; off; off >>= 1) {
      sd += __shfl_down(sd, off, 64);
      cgt += __shfl_down(cgt, off, 64);
    }
    __shared__ double rs[TPD / 64];
    __shared__ int rg[TPD / 64];
    if (lane == 0) { rs[wid] = sd; rg[wid] = cgt; }
    __syncthreads();
    if (threadIdx.x == 0) {
      double S = 0.0; int CG = 0;
      for (int i = 0; i < TPD / 64; ++i) { S += rs[i]; CG += rg[i]; }
      contrib = S + (double)vk * (double)(K - CG);
    }
  }

  // publish + last-block finalize
  __shared__ int last;
  if (threadIdx.x == 0) {
    __hip_atomic_store(&topC[b], contrib, __ATOMIC_RELEASE,
                       __HIP_MEMORY_SCOPE_AGENT);
    int prev = __hip_atomic_fetch_add(cnt, 1, __ATOMIC_ACQ_REL,
                                      __HIP_MEMORY_SCOPE_AGENT);
    last = (prev == BB - 1) ? 1 : 0;
  }
  __syncthreads();
  if (last && threadIdx.x == 0) {
    int n = 0;
    double sl = 0.0, sctot = 0.0;
    #pragma unroll 8
    for (int i = 0; i < BB; ++i) {
      n += num_pos[i];
      sl += accL[i];
      sctot += accC[i] + __hip_atomic_load(&topC[i], __ATOMIC_ACQUIRE,
                                           __HIP_MEMORY_SCOPE_AGENT);
    }
    double N = (double)max(n, 1);
    out[0] = (float)(sl / N);
    out[1] = (float)(sctot / N);
  }
}

extern "C" void kernel_launch(void* const* d_in, const int* in_sizes, int n_in,
                              void* d_out, int out_size, void* d_ws, size_t ws_size,
                              hipStream_t stream) {
  const float* loc     = (const float*)d_in[0];  // B*P*4
  const float* conf    = (const float*)d_in[1];  // B*P*21
  const float* priors  = (const float*)d_in[2];  // P*4
  const float* targets = (const float*)d_in[3];  // B*O*5
  float* out = (float*)d_out;

  char* ws = (char*)d_ws;
  double* accL = (double*)(ws + OFF_ACCL);
  double* accC = (double*)(ws + OFF_ACCC);
  int* num_pos = (int*)(ws + OFF_NP);
  int* cnt = (int*)(ws + OFF_CNT);
  double* topC = (double*)(ws + OFF_TOPC);
  unsigned long long* keys_part = (unsigned long long*)(ws + OFF_KP);
  float* lh = (float*)(ws + OFF_LH);

  dim3 gridM(MB, BB);
  match_kernel<<<gridM, MT, 0, stream>>>(priors, targets, keys_part,
                                         accL, accC, num_pos, cnt);
  dim3 gridL((PP + TPB - 1) / TPB, BB);
  loss_kernel<<<gridL, TPB, 0, stream>>>(loc, conf, priors, targets, keys_part,
                                         lh, accL, accC, num_pos);
  topk_kernel<<<BB, TPD, 0, stream>>>(lh, num_pos, topC, accL, accC, cnt, out);
}